// Round 8
// baseline (479.183 us; speedup 1.0000x reference)
//
#include <hip/hip_runtime.h>
#include <stdint.h>

#define BATCH  65536
#define IN_DIM 1024
#define MASKED 512
#define HIDDEN 1024

typedef unsigned short u16;
typedef __bf16 bf16x8 __attribute__((ext_vector_type(8)));
typedef float  f32x4  __attribute__((ext_vector_type(4)));

typedef __attribute__((address_space(1))) void gvoid;
typedef __attribute__((address_space(3))) void lvoid;

#define WAITV(N) asm volatile("s_waitcnt vmcnt(" #N ")" ::: "memory")
#define FENCE()  asm volatile("" ::: "memory")

__device__ __forceinline__ u16 f32_to_bf16(float f) {
    union { float f; uint32_t u; } v; v.f = f;
    uint32_t r = v.u + 0x7FFFu + ((v.u >> 16) & 1u);   // round-to-nearest-even
    return (u16)(r >> 16);
}

// ---------------------------------------------------------------------------
// prep: x (BATCH x IN_DIM f32) -> xm (BATCH x MASKED bf16)  [even columns]
// ---------------------------------------------------------------------------
__global__ void prep_xm(const float* __restrict__ x, u16* __restrict__ xm) {
    int idx = blockIdx.x * blockDim.x + threadIdx.x;
    const float4* xv = reinterpret_cast<const float4*>(x);
    float4 v0 = xv[idx * 2];
    float4 v1 = xv[idx * 2 + 1];
    ushort4 o;
    o.x = f32_to_bf16(v0.x);
    o.y = f32_to_bf16(v0.z);
    o.z = f32_to_bf16(v1.x);
    o.w = f32_to_bf16(v1.z);
    reinterpret_cast<ushort4*>(xm)[idx] = o;
}

// ---------------------------------------------------------------------------
// weight convert+transpose: W (K x N f32, row-major) -> Wt (N x K bf16)
// ---------------------------------------------------------------------------
__global__ void wconv(const float* __restrict__ W, u16* __restrict__ Wt,
                      int K, int N) {
    __shared__ float t[32][33];
    const int nbk = K / 32;
    const int bk = blockIdx.x % nbk;
    const int bn = blockIdx.x / nbk;
    const int tx = threadIdx.x & 31;
    const int ty = threadIdx.x >> 5;
    const int k0 = bk * 32, n0 = bn * 32;
    #pragma unroll
    for (int i = 0; i < 4; ++i)
        t[ty + i * 8][tx] = W[(int64_t)(k0 + ty + i * 8) * N + n0 + tx];
    __syncthreads();
    #pragma unroll
    for (int i = 0; i < 4; ++i)
        Wt[(int64_t)(n0 + ty + i * 8) * K + k0 + tx] = f32_to_bf16(t[tx][ty + i * 8]);
}

// ---------------------------------------------------------------------------
// Deep-pipelined GEMM (4-phase/K-step, 6-phase latency cover):
//   C(MxN) = A(MxK,bf16) @ Bt(NxK,bf16)^T + bias
// MODE 0: C = relu(.) -> bf16 Cb ;  MODE 1: coupling epilogue into Y.
//
// 256x256 tile, BK=64, 512 thr = 8 waves (2M x 4N), per-wave C = 128x64
// (8 M-frags x 4 N-frags of 16x16x32).  LDS = 2 K-step dbufs, each split
// into four 16KB k-half regions: A[p][kh] (256 rows x 32k), B[p][kh].
//
// Per K-step t (buf p=t&1), 4 phases, 16 MFMA each:
//   P1 {kh0, mf0-3 + B-read}  stage A-kh1(t+1) -> buf p^1   [dead (t-1).P4]
//   P2 {kh0, mf4-7, B reuse}  stage B-kh0(t+2) -> buf p     [dead t.P1]
//   P3 {kh1, mf0-3 + B-read}  stage A-kh0(t+2) -> buf p     [dead t.P2]
//   P4 {kh1, mf4-7, B reuse}  stage B-kh1(t+2) -> buf p     [dead t.P3]
// Each stage = 2 x global_load_lds(16B); issue->first-read distance is
// 6-7 phases (~1100-1400 cyc > 900-cyc HBM latency; R4's failure was a
// 620-cyc window).  Gates: vmcnt(10) at P2/P4 ends only (exact FIFO
// accounting incl. prologue); vmcnt(0) only in the 2-step tail.
//
// Swizzle (R4/R6-proven involution class, 32-k rows = 4 chunks of 16B):
// lds chunk d holds global chunk d ^ ((row>>1)&3); applied on the per-lane
// GLOBAL source (DMA stays linear) and on the ds_read chunk.  Fragment
// reads then touch bank-group (4*cl + d) mod 8: all 8 groups x 2 = free.
// ---------------------------------------------------------------------------
template<int K, int N, int MODE>
__global__ __launch_bounds__(512, 2)
void gemm8p(const u16* __restrict__ A, const u16* __restrict__ Bt,
            const float* __restrict__ bias,
            u16* __restrict__ Cb,
            const float* __restrict__ X,
            float* __restrict__ Y) {
    constexpr int NT = K / 64;
    __shared__ __align__(16) u16 Ls[65536];   // [A: 2x16384][B: +32768]

    const int tid  = threadIdx.x;
    const int lane = tid & 63;
    const int w    = tid >> 6;
    const int wm   = w >> 2;        // 0..1
    const int wn   = w & 3;         // 0..3

    // T1: XCD swizzle (grids are multiples of 8 -> bijective)
    const int nwg = gridDim.x;
    const int cpx = nwg >> 3;
    const int bid = (blockIdx.x & 7) * cpx + (blockIdx.x >> 3);
    constexpr int nbn = N / 256;
    const int m0 = (bid / nbn) * 256;
    const int n0 = (bid % nbn) * 256;

    const u16* aPanel = A  + (int64_t)m0 * K;
    const u16* bPanel = Bt + (int64_t)n0 * K;

    // stage one 16KB k-half region: 1024 chunks of 16B, 2 loads/thread
    auto stage = [&](int arrBase, int pp, int kh, const u16* gbase, int koff) {
        #pragma unroll
        for (int i = 0; i < 2; ++i) {
            const int c = i * 512 + tid;
            const int row = c >> 2;
            const int cq = (c & 3) ^ ((row >> 1) & 3);   // pre-swizzled source
            __builtin_amdgcn_global_load_lds(
                (gvoid*)(gbase + (int64_t)row * K + koff + cq * 8),
                (lvoid*)(&Ls[arrBase + pp * 16384 + kh * 8192 + c * 8]), 16, 0, 0);
        }
    };

    f32x4 acc[8][4];
    #pragma unroll
    for (int i = 0; i < 8; ++i)
        #pragma unroll
        for (int j = 0; j < 4; ++j)
            acc[i][j] = f32x4{0.f, 0.f, 0.f, 0.f};

    // prologue: steps 0 and 1 fully staged (FIFO order matters for gates)
    stage(0,     0, 0, aPanel, 0);    // A-kh0(0)
    stage(0,     0, 1, aPanel, 32);   // A-kh1(0)
    stage(32768, 0, 0, bPanel, 0);    // B-kh0(0)
    stage(32768, 0, 1, bPanel, 32);   // B-kh1(0)
    stage(0,     1, 0, aPanel, 64);   // A-kh0(1)
    stage(32768, 1, 0, bPanel, 64);   // B-kh0(1)
    stage(0,     1, 1, aPanel, 96);   // A-kh1(1)
    stage(32768, 1, 1, bPanel, 96);   // B-kh1(1)
    WAITV(8);                          // step 0 fully landed
    __builtin_amdgcn_s_barrier(); FENCE();

    // fragment read addressing (u16 elem offsets; all 16B-aligned)
    const int cl  = lane & 15;
    const int rc  = (((lane >> 4) ^ ((cl >> 1) & 3))) * 8;  // swizzled chunk
    const int aR0 = (wm * 128 + cl) * 32;
    const int bR0 = (wn * 64 + cl) * 32;

    for (int t = 0; t < NT; ++t) {
        const int p = t & 1;
        const int ab = p * 16384;            // A buf base
        const int bb = 32768 + p * 16384;    // B buf base
        bf16x8 a[4], b[4];

        // ---------------- P1: kh0, mf0-3 ----------------
        #pragma unroll
        for (int mf = 0; mf < 4; ++mf)
            a[mf] = *(const bf16x8*)&Ls[ab + aR0 + mf * 512 + rc];
        #pragma unroll
        for (int nf = 0; nf < 4; ++nf)
            b[nf] = *(const bf16x8*)&Ls[bb + bR0 + nf * 512 + rc];
        if (t >= 1 && t + 1 < NT) stage(0, (t + 1) & 1, 1, aPanel, (t + 1) * 64 + 32);
        __builtin_amdgcn_s_setprio(1);
        #pragma unroll
        for (int mf = 0; mf < 4; ++mf)
            #pragma unroll
            for (int nf = 0; nf < 4; ++nf)
                acc[mf][nf] = __builtin_amdgcn_mfma_f32_16x16x32_bf16(
                    a[mf], b[nf], acc[mf][nf], 0, 0, 0);
        __builtin_amdgcn_s_setprio(0);
        __builtin_amdgcn_s_barrier(); FENCE();

        // ---------------- P2: kh0, mf4-7 (b reuse) ----------------
        #pragma unroll
        for (int mf = 0; mf < 4; ++mf)
            a[mf] = *(const bf16x8*)&Ls[ab + aR0 + 64 * 32 + mf * 512 + rc];
        if (t + 2 < NT) stage(32768, p, 0, bPanel, (t + 2) * 64);
        __builtin_amdgcn_s_setprio(1);
        #pragma unroll
        for (int mf = 0; mf < 4; ++mf)
            #pragma unroll
            for (int nf = 0; nf < 4; ++nf)
                acc[mf + 4][nf] = __builtin_amdgcn_mfma_f32_16x16x32_bf16(
                    a[mf], b[nf], acc[mf + 4][nf], 0, 0, 0);
        __builtin_amdgcn_s_setprio(0);
        if (t + 2 < NT) { WAITV(10); } else { WAITV(0); }
        __builtin_amdgcn_s_barrier(); FENCE();

        // ---------------- P3: kh1, mf0-3 ----------------
        #pragma unroll
        for (int mf = 0; mf < 4; ++mf)
            a[mf] = *(const bf16x8*)&Ls[ab + 8192 + aR0 + mf * 512 + rc];
        #pragma unroll
        for (int nf = 0; nf < 4; ++nf)
            b[nf] = *(const bf16x8*)&Ls[bb + 8192 + bR0 + nf * 512 + rc];
        if (t + 2 < NT) stage(0, p, 0, aPanel, (t + 2) * 64);
        __builtin_amdgcn_s_setprio(1);
        #pragma unroll
        for (int mf = 0; mf < 4; ++mf)
            #pragma unroll
            for (int nf = 0; nf < 4; ++nf)
                acc[mf][nf] = __builtin_amdgcn_mfma_f32_16x16x32_bf16(
                    a[mf], b[nf], acc[mf][nf], 0, 0, 0);
        __builtin_amdgcn_s_setprio(0);
        __builtin_amdgcn_s_barrier(); FENCE();

        // ---------------- P4: kh1, mf4-7 (b reuse) ----------------
        #pragma unroll
        for (int mf = 0; mf < 4; ++mf)
            a[mf] = *(const bf16x8*)&Ls[ab + 8192 + aR0 + 64 * 32 + mf * 512 + rc];
        if (t + 2 < NT) stage(32768, p, 1, bPanel, (t + 2) * 64 + 32);
        __builtin_amdgcn_s_setprio(1);
        #pragma unroll
        for (int mf = 0; mf < 4; ++mf)
            #pragma unroll
            for (int nf = 0; nf < 4; ++nf)
                acc[mf + 4][nf] = __builtin_amdgcn_mfma_f32_16x16x32_bf16(
                    a[mf], b[nf], acc[mf + 4][nf], 0, 0, 0);
        __builtin_amdgcn_s_setprio(0);
        if (t + 2 < NT) { WAITV(10); } else { WAITV(0); }
        __builtin_amdgcn_s_barrier(); FENCE();
    }

    // epilogue. C/D layout (m89-verified): col = lane&15, row = (lane>>4)*4+reg
    const int rg = (lane >> 4) * 4;
    #pragma unroll
    for (int nf = 0; nf < 4; ++nf) {
        const int n  = n0 + wn * 64 + nf * 16 + cl;
        const float bv = bias[n];
        #pragma unroll
        for (int mf = 0; mf < 8; ++mf) {
            #pragma unroll
            for (int r = 0; r < 4; ++r) {
                const int m = m0 + wm * 128 + mf * 16 + rg + r;
                float v = acc[mf][nf][r] + bv;
                if (MODE == 0) {
                    v = v > 0.f ? v : 0.f;
                    Cb[(int64_t)m * N + n] = f32_to_bf16(v);
                } else {
                    const int64_t pp = (int64_t)m * IN_DIM + 2 * n;
                    float2 xv = *reinterpret_cast<const float2*>(&X[pp]);
                    float2 o;
                    o.x = xv.x;          // even column: exact copy
                    o.y = xv.y + v;      // odd column: x + translation
                    *reinterpret_cast<float2*>(&Y[pp]) = o;
                }
            }
        }
    }
}

// ---------------------------------------------------------------------------
extern "C" void kernel_launch(void* const* d_in, const int* in_sizes, int n_in,
                              void* d_out, int out_size, void* d_ws, size_t ws_size,
                              hipStream_t stream) {
    const float* x  = (const float*)d_in[0];
    const float* W1 = (const float*)d_in[1];
    const float* b1 = (const float*)d_in[2];
    const float* W2 = (const float*)d_in[3];
    const float* b2 = (const float*)d_in[4];
    const float* W3 = (const float*)d_in[5];
    const float* b3 = (const float*)d_in[6];
    float* y = (float*)d_out;

    char* ws = (char*)d_ws;
    // layout: h1 (128MB) | h2 (128MB, first 64MB aliased by xm) | W1t|W2t|W3t
    u16* h1  = (u16*)(ws);
    u16* h2  = (u16*)(ws + 134217728);
    u16* xm  = (u16*)(ws + 134217728);                 // dead before h2 is written
    u16* W1t = (u16*)(ws + 268435456);
    u16* W2t = (u16*)(ws + 268435456 + 1048576);
    u16* W3t = (u16*)(ws + 268435456 + 1048576 + 2097152);

    // 1) extract even columns -> bf16
    prep_xm<<<BATCH * IN_DIM / 8 / 256, 256, 0, stream>>>(x, xm);

    // 2) convert + transpose weights to bf16 N x K
    wconv<<<(MASKED / 32) * (HIDDEN / 32), 256, 0, stream>>>(W1, W1t, MASKED, HIDDEN);
    wconv<<<(HIDDEN / 32) * (HIDDEN / 32), 256, 0, stream>>>(W2, W2t, HIDDEN, HIDDEN);
    wconv<<<(HIDDEN / 32) * ((IN_DIM - MASKED) / 32), 256, 0, stream>>>(W3, W3t, HIDDEN, IN_DIM - MASKED);

    // 3) three deep-pipelined GEMMs (grids 1024/1024/512, all %8==0)
    gemm8p<MASKED, HIDDEN, 0><<<(BATCH / 256) * (HIDDEN / 256), 512, 0, stream>>>(
        xm, W1t, b1, h1, nullptr, nullptr);
    gemm8p<HIDDEN, HIDDEN, 0><<<(BATCH / 256) * (HIDDEN / 256), 512, 0, stream>>>(
        h1, W2t, b2, h2, nullptr, nullptr);
    gemm8p<HIDDEN, IN_DIM - MASKED, 1><<<(BATCH / 256) * ((IN_DIM - MASKED) / 256), 512, 0, stream>>>(
        h2, W3t, b3, nullptr, x, y);
}